// Round 5
// baseline (194.545 us; speedup 1.0000x reference)
//
#include <hip/hip_runtime.h>
#include <hip/hip_bf16.h>

#define NN 512      // nodes per graph
#define NE 8192     // edges per graph
#define NG 128      // graphs (B*G)
#define FH 128      // feature/hidden dim
#define XPITCH 136  // LDS ushort pitch for 128-wide rows (16B-aligned, bank-skewed)
#define BN_EPS 1e-5f

typedef __attribute__((ext_vector_type(8))) short s8v;            // 8 bf16 = 4 VGPRs
typedef __attribute__((ext_vector_type(4))) float f4v;            // MFMA C/D
typedef __attribute__((ext_vector_type(8))) unsigned short us8v;  // 8 ushort = 16B

__device__ inline unsigned short f2bf(float x) {   // RNE fp32 -> bf16 bits
    unsigned u = __float_as_uint(x);
    unsigned r = (u + 0x7fffu + ((u >> 16) & 1u)) >> 16;
    return (unsigned short)r;
}
__device__ inline float bf2f(unsigned short h) { return __uint_as_float(((unsigned)h) << 16); }

// ---------------- K1: degrees + norms + dst-sorted CSR (src only); blocks >= NG pack W ----------------
__global__ __launch_bounds__(1024) void k_build(const int* __restrict__ edges,
                                                float* __restrict__ rs_out,
                                                float* __restrict__ rs_in,
                                                int* __restrict__ row_ofs,
                                                int* __restrict__ csr_src,
                                                const float* __restrict__ W0,
                                                const float* __restrict__ W1,
                                                unsigned short* __restrict__ WP) {
    int g = blockIdx.x;
    int tid = threadIdx.x;

    if (g >= NG) {
        int which = g - NG;
        const float* W = which ? W1 : W0;
        for (int task = tid; task < 2048; task += 1024) {
            int t = task >> 6;            // 0..31  (nt*4+kk)
            int lane = task & 63;
            int nt = t >> 2, kk = t & 3;
            int n = nt * 16 + (lane & 15);
            int k0 = kk * 32 + (lane >> 4) * 8;
            unsigned short* dh = WP + ((size_t)which * 2 + 0) * 16384 + ((size_t)t * 64 + lane) * 8;
            unsigned short* dl = WP + ((size_t)which * 2 + 1) * 16384 + ((size_t)t * 64 + lane) * 8;
#pragma unroll
            for (int j = 0; j < 8; j++) {
                float v = W[(size_t)(k0 + j) * FH + n];
                unsigned short h = f2bf(v);
                dh[j] = h;
                dl[j] = f2bf(v - bf2f(h));
            }
        }
        return;
    }

    const int* src = edges + (size_t)g * 2 * NE;
    const int* dst = src + NE;

    __shared__ int degO[NN], degI[NN];
    __shared__ int scanA[NN], scanB[NN];
    __shared__ int fill[NN];
    __shared__ int csr_lds[NE];          // 32 KB

    for (int i = tid; i < NN; i += 1024) { degO[i] = 0; degI[i] = 0; }
    __syncthreads();
    for (int u = tid; u < NE / 4; u += 1024) {
        int4 s = ((const int4*)src)[u];
        int4 d = ((const int4*)dst)[u];
        atomicAdd(&degO[s.x], 1); atomicAdd(&degO[s.y], 1);
        atomicAdd(&degO[s.z], 1); atomicAdd(&degO[s.w], 1);
        atomicAdd(&degI[d.x], 1); atomicAdd(&degI[d.y], 1);
        atomicAdd(&degI[d.z], 1); atomicAdd(&degI[d.w], 1);
    }
    __syncthreads();
    for (int i = tid; i < NN; i += 1024) {
        rs_out[g * NN + i] = rsqrtf((float)max(degO[i], 1));
        rs_in [g * NN + i] = rsqrtf((float)max(degI[i], 1));
        scanA[i] = degI[i];
    }
    __syncthreads();
    int* sA = scanA; int* sB = scanB;
    for (int off = 1; off < NN; off <<= 1) {
        for (int i = tid; i < NN; i += 1024) {
            int v = sA[i];
            if (i >= off) v += sA[i - off];
            sB[i] = v;
        }
        __syncthreads();
        int* t = sA; sA = sB; sB = t;
    }
    for (int i = tid; i < NN; i += 1024) {
        int excl = (i == 0) ? 0 : sA[i - 1];
        fill[i] = excl;
        row_ofs[g * 513 + i] = excl;
    }
    if (tid == 0) row_ofs[g * 513 + NN] = NE;
    __syncthreads();
    for (int u = tid; u < NE / 4; u += 1024) {
        int4 s = ((const int4*)src)[u];
        int4 d = ((const int4*)dst)[u];
        int p0 = atomicAdd(&fill[d.x], 1); csr_lds[p0] = s.x;
        int p1 = atomicAdd(&fill[d.y], 1); csr_lds[p1] = s.y;
        int p2 = atomicAdd(&fill[d.z], 1); csr_lds[p2] = s.z;
        int p3 = atomicAdd(&fill[d.w], 1); csr_lds[p3] = s.w;
    }
    __syncthreads();
    for (int u = tid; u < NE / 4; u += 1024)
        ((int4*)(csr_src + (size_t)g * NE))[u] = ((const int4*)csr_lds)[u];
}

// ---------------- K2: Y1 = bf16_rowmajor((feats @ W0) * rs_out)  (hi/lo split, 3 MFMA) ----------------
__global__ __launch_bounds__(256) void k_gemm_f32(const float* __restrict__ X,
                                                  const unsigned short* __restrict__ WPh,
                                                  const unsigned short* __restrict__ WPl,
                                                  const float* __restrict__ rs,
                                                  unsigned short* __restrict__ Yf) {
    __shared__ unsigned short xb[2 * 64 * XPITCH];   // xh | xl; reused as float Lf[64*132]
    unsigned short* xh = xb;
    unsigned short* xl = xb + 64 * XPITCH;
    float* Lf = (float*)xb;                          // 64*132*4 = 33792 B <= 34816 B
    int tid = threadIdx.x;
    int sb = blockIdx.y;
    size_t r0 = (size_t)blockIdx.x * NN + (size_t)sb * 64;

    const float4* Xv = (const float4*)(X + r0 * FH);
#pragma unroll
    for (int i = 0; i < 8; i++) {
        int u = tid + i * 256;                 // 2048 float4 = 64x128
        int row = u >> 5, c4 = (u & 31) * 4;
        float4 v = Xv[u];
        int off = row * XPITCH + c4;
        unsigned short h0 = f2bf(v.x), h1 = f2bf(v.y), h2 = f2bf(v.z), h3 = f2bf(v.w);
        xh[off + 0] = h0; xh[off + 1] = h1; xh[off + 2] = h2; xh[off + 3] = h3;
        xl[off + 0] = f2bf(v.x - bf2f(h0));
        xl[off + 1] = f2bf(v.y - bf2f(h1));
        xl[off + 2] = f2bf(v.z - bf2f(h2));
        xl[off + 3] = f2bf(v.w - bf2f(h3));
    }
    __syncthreads();

    int lane = tid & 63, w = tid >> 6;
    int quad = lane >> 4, m = lane & 15;
    int arow = w * 16 + m;

    f4v acc[8];
#pragma unroll
    for (int nt = 0; nt < 8; nt++) acc[nt] = (f4v){0.f, 0.f, 0.f, 0.f};

#pragma unroll
    for (int kk = 0; kk < 4; kk++) {
        s8v ah = *(const s8v*)&xh[arow * XPITCH + kk * 32 + quad * 8];
        s8v al = *(const s8v*)&xl[arow * XPITCH + kk * 32 + quad * 8];
#pragma unroll
        for (int nt = 0; nt < 8; nt++) {
            s8v bh = *(const s8v*)(WPh + ((size_t)(nt * 4 + kk) * 64 + lane) * 8);
            s8v bl = *(const s8v*)(WPl + ((size_t)(nt * 4 + kk) * 64 + lane) * 8);
            acc[nt] = __builtin_amdgcn_mfma_f32_16x16x32_bf16(ah, bh, acc[nt], 0, 0, 0);
            acc[nt] = __builtin_amdgcn_mfma_f32_16x16x32_bf16(al, bh, acc[nt], 0, 0, 0);
            acc[nt] = __builtin_amdgcn_mfma_f32_16x16x32_bf16(ah, bl, acc[nt], 0, 0, 0);
        }
    }
    __syncthreads();   // all xh/xl reads done; reuse as Lf

    // C*rs -> Lf (row-major f32), then coalesced bf16 row-major store
    int orow = w * 16 + quad * 4;
    float4 rsv = *(const float4*)(rs + r0 + orow);
#pragma unroll
    for (int nt = 0; nt < 8; nt++) {
        Lf[(orow + 0) * 132 + nt * 16 + m] = acc[nt][0] * rsv.x;
        Lf[(orow + 1) * 132 + nt * 16 + m] = acc[nt][1] * rsv.y;
        Lf[(orow + 2) * 132 + nt * 16 + m] = acc[nt][2] * rsv.z;
        Lf[(orow + 3) * 132 + nt * 16 + m] = acc[nt][3] * rsv.w;
    }
    __syncthreads();
#pragma unroll
    for (int u0 = 0; u0 < 4; u0++) {
        int u = tid + u0 * 256;                // 1024 units: 64 rows x 16 chunks of 8 feats
        int row = u >> 4, c8 = (u & 15) * 8;
        const float* p = &Lf[row * 132 + c8];
        us8v v;
#pragma unroll
        for (int j = 0; j < 8; j++) v[j] = f2bf(p[j]);
        *(us8v*)(Yf + (r0 + row) * FH + c8) = v;
    }
}

// ---------------- K3: register-gather CSR aggregation + relu/bias -> hs -> MFMA gemm2 -> Y2 (row-major) ----------------
// 16-lane group owns dst rows; per edge: one coalesced 16B gather of the src row (L2-resident
// row-major Y1), bf16 unpack by shift, f32 adds in regs. No A-build/zero/staging/pass barriers.
__global__ __launch_bounds__(512) void k_fused(const unsigned short* __restrict__ Y1f,
                                               const int* __restrict__ row_ofs,
                                               const int* __restrict__ csr_src,
                                               const float* __restrict__ rs_in,
                                               const float* __restrict__ rs_out,
                                               const float* __restrict__ bias,
                                               const unsigned short* __restrict__ WPh,
                                               const unsigned short* __restrict__ WPl,
                                               unsigned short* __restrict__ Y2f) {
    int g  = blockIdx.x;
    int sb = blockIdx.y;   // 0..3 -> 128 dst rows each
    int tid = threadIdx.x;
    int base = sb * 128;

    __shared__ unsigned short hs[128 * XPITCH];  // 34816 B; A of gemm2, then output staging
    __shared__ int   ro_s[129];
    __shared__ float rsin_s[128], rsout_s[128], b_s[128];

    if (tid < 129) ro_s[tid] = row_ofs[g * 513 + base + tid];
    if (tid < 128) {
        rsin_s[tid]  = rs_in [g * NN + base + tid];
        rsout_s[tid] = rs_out[g * NN + base + tid];
        b_s[tid]     = bias[tid];
    }
    __syncthreads();

    const unsigned short* Yg = Y1f + (size_t)g * (NN * FH);
    const int* cs = csr_src + (size_t)g * NE;
    int gid = tid >> 4, l = tid & 15;            // 32 groups x 16 lanes

#pragma unroll
    for (int k = 0; k < 4; k++) {
        int r = gid * 4 + k;
        int e0 = ro_s[r], e1 = ro_s[r + 1];
        float a0 = 0.f, a1 = 0.f, a2 = 0.f, a3 = 0.f, a4 = 0.f, a5 = 0.f, a6 = 0.f, a7 = 0.f;
        int s = (e0 < e1) ? cs[e0] : 0;
        for (int e = e0; e < e1; e++) {
            int4 d = *(const int4*)(Yg + (size_t)s * FH + l * 8);
            if (e + 1 < e1) s = cs[e + 1];       // prefetch next src idx
            a0 += __uint_as_float((unsigned)d.x << 16);
            a1 += __uint_as_float((unsigned)d.x & 0xffff0000u);
            a2 += __uint_as_float((unsigned)d.y << 16);
            a3 += __uint_as_float((unsigned)d.y & 0xffff0000u);
            a4 += __uint_as_float((unsigned)d.z << 16);
            a5 += __uint_as_float((unsigned)d.z & 0xffff0000u);
            a6 += __uint_as_float((unsigned)d.w << 16);
            a7 += __uint_as_float((unsigned)d.w & 0xffff0000u);
        }
        float rv = rsin_s[r];
        us8v hv;
        hv[0] = f2bf(fmaxf(fmaf(rv, a0, b_s[l * 8 + 0]), 0.f));
        hv[1] = f2bf(fmaxf(fmaf(rv, a1, b_s[l * 8 + 1]), 0.f));
        hv[2] = f2bf(fmaxf(fmaf(rv, a2, b_s[l * 8 + 2]), 0.f));
        hv[3] = f2bf(fmaxf(fmaf(rv, a3, b_s[l * 8 + 3]), 0.f));
        hv[4] = f2bf(fmaxf(fmaf(rv, a4, b_s[l * 8 + 4]), 0.f));
        hv[5] = f2bf(fmaxf(fmaf(rv, a5, b_s[l * 8 + 5]), 0.f));
        hv[6] = f2bf(fmaxf(fmaf(rv, a6, b_s[l * 8 + 6]), 0.f));
        hv[7] = f2bf(fmaxf(fmaf(rv, a7, b_s[l * 8 + 7]), 0.f));
        *(us8v*)&hs[r * XPITCH + l * 8] = hv;
    }
    __syncthreads();

    // ---- gemm2: Y2 = (h @ W1) * rs_out; 8 waves, wave w owns rows w*16..w*16+15, all 8 nt ----
    int lane = tid & 63, w = tid >> 6;
    int quad = lane >> 4, m = lane & 15;

    f4v acc2[8];
#pragma unroll
    for (int nt = 0; nt < 8; nt++) acc2[nt] = (f4v){0.f, 0.f, 0.f, 0.f};

#pragma unroll
    for (int kk = 0; kk < 4; kk++) {
        s8v ah = *(const s8v*)&hs[(w * 16 + m) * XPITCH + kk * 32 + quad * 8];
#pragma unroll
        for (int nt = 0; nt < 8; nt++) {
            s8v bh = *(const s8v*)(WPh + ((size_t)(nt * 4 + kk) * 64 + lane) * 8);
            s8v bl = *(const s8v*)(WPl + ((size_t)(nt * 4 + kk) * 64 + lane) * 8);
            acc2[nt] = __builtin_amdgcn_mfma_f32_16x16x32_bf16(ah, bh, acc2[nt], 0, 0, 0);
            acc2[nt] = __builtin_amdgcn_mfma_f32_16x16x32_bf16(ah, bl, acc2[nt], 0, 0, 0);
        }
    }
    __syncthreads();   // hs reads done; reuse for output staging

    int orow = w * 16 + quad * 4;
#pragma unroll
    for (int nt = 0; nt < 8; nt++) {
#pragma unroll
        for (int i = 0; i < 4; i++)
            hs[(orow + i) * XPITCH + nt * 16 + m] = f2bf(acc2[nt][i] * rsout_s[orow + i]);
    }
    __syncthreads();
    unsigned short* of = Y2f + (size_t)g * (NN * FH) + (size_t)base * FH;
#pragma unroll
    for (int u0 = 0; u0 < 4; u0++) {
        int u = tid + u0 * 512;                // 2048 units: 128 rows x 16 chunks of 8 feats
        int row = u >> 4, c8 = (u & 15) * 8;
        *(int4*)(of + row * FH + c8) = *(const int4*)&hs[row * XPITCH + c8];
    }
}

// ---------------- K4: register-gather CSR aggregation (conv2) + relu + node-sum -> partial ----------------
__global__ __launch_bounds__(512) void k_gather_mean(const unsigned short* __restrict__ Y2f,
                                                     const int* __restrict__ row_ofs,
                                                     const int* __restrict__ csr_src,
                                                     const float* __restrict__ rs_in,
                                                     const float* __restrict__ bias,
                                                     float* __restrict__ partial) {
    int g  = blockIdx.x;
    int sb = blockIdx.y;   // 0..3
    int tid = threadIdx.x;
    int base = sb * 128;

    __shared__ float red[32 * 16 * 8];   // 16 KB
    __shared__ int   ro_s[129];
    __shared__ float rsin_s[128], b_s[128];

    if (tid < 129) ro_s[tid] = row_ofs[g * 513 + base + tid];
    if (tid < 128) {
        rsin_s[tid] = rs_in[g * NN + base + tid];
        b_s[tid]    = bias[tid];
    }
    __syncthreads();

    const unsigned short* Yg = Y2f + (size_t)g * (NN * FH);
    const int* cs = csr_src + (size_t)g * NE;
    int gid = tid >> 4, l = tid & 15;

    float s0 = 0.f, s1 = 0.f, s2 = 0.f, s3 = 0.f, s4 = 0.f, s5 = 0.f, s6 = 0.f, s7 = 0.f;
#pragma unroll
    for (int k = 0; k < 4; k++) {
        int r = gid * 4 + k;
        int e0 = ro_s[r], e1 = ro_s[r + 1];
        float a0 = 0.f, a1 = 0.f, a2 = 0.f, a3 = 0.f, a4 = 0.f, a5 = 0.f, a6 = 0.f, a7 = 0.f;
        int s = (e0 < e1) ? cs[e0] : 0;
        for (int e = e0; e < e1; e++) {
            int4 d = *(const int4*)(Yg + (size_t)s * FH + l * 8);
            if (e + 1 < e1) s = cs[e + 1];
            a0 += __uint_as_float((unsigned)d.x << 16);
            a1 += __uint_as_float((unsigned)d.x & 0xffff0000u);
            a2 += __uint_as_float((unsigned)d.y << 16);
            a3 += __uint_as_float((unsigned)d.y & 0xffff0000u);
            a4 += __uint_as_float((unsigned)d.z << 16);
            a5 += __uint_as_float((unsigned)d.z & 0xffff0000u);
            a6 += __uint_as_float((unsigned)d.w << 16);
            a7 += __uint_as_float((unsigned)d.w & 0xffff0000u);
        }
        float rv = rsin_s[r];
        s0 += fmaxf(fmaf(rv, a0, b_s[l * 8 + 0]), 0.f);
        s1 += fmaxf(fmaf(rv, a1, b_s[l * 8 + 1]), 0.f);
        s2 += fmaxf(fmaf(rv, a2, b_s[l * 8 + 2]), 0.f);
        s3 += fmaxf(fmaf(rv, a3, b_s[l * 8 + 3]), 0.f);
        s4 += fmaxf(fmaf(rv, a4, b_s[l * 8 + 4]), 0.f);
        s5 += fmaxf(fmaf(rv, a5, b_s[l * 8 + 5]), 0.f);
        s6 += fmaxf(fmaf(rv, a6, b_s[l * 8 + 6]), 0.f);
        s7 += fmaxf(fmaf(rv, a7, b_s[l * 8 + 7]), 0.f);
    }
    float* rp = &red[(gid * 16 + l) * 8];
    rp[0] = s0; rp[1] = s1; rp[2] = s2; rp[3] = s3;
    rp[4] = s4; rp[5] = s5; rp[6] = s6; rp[7] = s7;
    __syncthreads();
    if (tid < FH) {
        int f = tid, ll = f >> 3, j = f & 7;
        float t = 0.f;
#pragma unroll
        for (int grp = 0; grp < 32; grp++)
            t += red[(grp * 16 + ll) * 8 + j];
        partial[((size_t)g * 4 + sb) * FH + f] = t;
    }
}

// ---------------- K5: z = (sum partials)/512 @ Wt + bt; BN eval; relu ----------------
__global__ __launch_bounds__(128) void k_head(const float* __restrict__ partial,
                                              const float* __restrict__ Wt,
                                              const float* __restrict__ bt,
                                              const float* __restrict__ gamma,
                                              const float* __restrict__ beta,
                                              const float* __restrict__ rmean,
                                              const float* __restrict__ rvar,
                                              float* __restrict__ out) {
    int g = blockIdx.x;
    int j = threadIdx.x;
    __shared__ float e[FH];
    float acc4 = 0.f;
#pragma unroll
    for (int q = 0; q < 4; q++) acc4 += partial[((size_t)g * 4 + q) * FH + j];
    e[j] = acc4 * (1.0f / (float)NN);
    __syncthreads();
    float acc = bt[j];
#pragma unroll 8
    for (int k = 0; k < FH; k++) acc += e[k] * Wt[(size_t)k * FH + j];
    float z = gamma[j] * (acc - rmean[j]) * rsqrtf(rvar[j] + BN_EPS) + beta[j];
    out[g * FH + j] = fmaxf(z, 0.f);
}

extern "C" void kernel_launch(void* const* d_in, const int* in_sizes, int n_in,
                              void* d_out, int out_size, void* d_ws, size_t ws_size,
                              hipStream_t stream) {
    const float* feats = (const float*)d_in[0];
    const int*   edges = (const int*)d_in[1];
    const float* W0    = (const float*)d_in[2];
    const float* b0    = (const float*)d_in[3];
    const float* W1    = (const float*)d_in[4];
    const float* b1    = (const float*)d_in[5];
    const float* Wt    = (const float*)d_in[6];
    const float* bt    = (const float*)d_in[7];
    const float* gamma = (const float*)d_in[8];
    const float* beta  = (const float*)d_in[9];
    const float* rmean = (const float*)d_in[10];
    const float* rvar  = (const float*)d_in[11];
    float* out = (float*)d_out;

    // workspace layout
    char* w = (char*)d_ws;
    float* rs_out  = (float*)w;   w += sizeof(float) * NG * NN;
    float* rs_in   = (float*)w;   w += sizeof(float) * NG * NN;
    int*   row_ofs = (int*)w;     w += sizeof(int) * NG * 513;             // 262656 B (16B multiple)
    int*   csr_src = (int*)w;     w += sizeof(int) * (size_t)NG * NE;      // 4 MB
    unsigned short* WP  = (unsigned short*)w; w += sizeof(unsigned short) * 4 * 16384;       // 128 KB
    unsigned short* Y1  = (unsigned short*)w; w += sizeof(unsigned short) * (size_t)NG * NN * FH; // 16 MB row-major
    unsigned short* Y2  = (unsigned short*)w; w += sizeof(unsigned short) * (size_t)NG * NN * FH; // 16 MB row-major
    float* partial = (float*)w;   w += sizeof(float) * NG * 4 * FH;

    unsigned short* WPh0 = WP;
    unsigned short* WPl0 = WP + 16384;
    unsigned short* WPh1 = WP + 32768;
    unsigned short* WPl1 = WP + 49152;

    // K1: norms + dst-sorted CSR; 2 extra blocks pack W0/W1
    k_build<<<NG + 2, 1024, 0, stream>>>(edges, rs_out, rs_in, row_ofs, csr_src, W0, W1, WP);

    // K2: conv1 gemm (feats -> Y1 row-major bf16, rs_out folded)
    k_gemm_f32<<<dim3(NG, 8), 256, 0, stream>>>(feats, WPh0, WPl0, rs_out, Y1);

    // K3: gather-aggregation (conv1 epilogue) + conv2 gemm -> Y2 row-major
    k_fused<<<dim3(NG, 4), 512, 0, stream>>>(Y1, row_ofs, csr_src, rs_in, rs_out, b0,
                                             WPh1, WPl1, Y2);

    // K4: gather-aggregation (conv2 epilogue) + node-sum -> partial
    k_gather_mean<<<dim3(NG, 4), 512, 0, stream>>>(Y2, row_ofs, csr_src, rs_in, b1, partial);

    // K5: head
    k_head<<<NG, 128, 0, stream>>>(partial, Wt, bt, gamma, beta, rmean, rvar, out);

    (void)in_sizes; (void)n_in; (void)out_size; (void)ws_size;
}